// Round 7
// baseline (235.196 us; speedup 1.0000x reference)
//
#include <hip/hip_runtime.h>
#include <hip/hip_bf16.h>
#include <stdint.h>

// ---------------------------------------------------------------------------
// U_GCN: 2x (4-head GAT layer -> 1-head GAT out layer) + semantic attention.
// N=4096, Fin=256, H=4, Fh=64, Ff=64, P=16. Masks ~0.5% dense + diagonal.
// R7: A/B probe on the 1.6TB/s mask-read wall. sadj is SDMA-copied to ws;
// k_adjA builds graph0 adjacency from the ws copy, k_adjB builds graph1 from
// d_in directly -- identical code, different buffer. One-pass block-per-row
// adjacency build (no bitmap, no compact, no atomics, deterministic order).
// ---------------------------------------------------------------------------

typedef short short8 __attribute__((ext_vector_type(8)));
typedef __bf16 bf16x8 __attribute__((ext_vector_type(8)));
typedef float floatx4 __attribute__((ext_vector_type(4)));
typedef unsigned int uintx4 __attribute__((ext_vector_type(4)));

#define MAXDEG 128
#define LRELU 0.2f

template <typename V>
__device__ inline auto mfma_impl(V a, V b, floatx4 c, int)
    -> decltype(__builtin_amdgcn_mfma_f32_16x16x32_bf16(a, b, c, 0, 0, 0)) {
  return __builtin_amdgcn_mfma_f32_16x16x32_bf16(a, b, c, 0, 0, 0);
}
template <typename V>
__device__ inline floatx4 mfma_impl(V a, V b, floatx4 c, long) {
  return __builtin_amdgcn_mfma_f32_16x16x32_bf16(
      __builtin_bit_cast(bf16x8, a), __builtin_bit_cast(bf16x8, b), c, 0, 0, 0);
}
__device__ inline floatx4 MFMA16(short8 a, short8 b, floatx4 c) {
  return mfma_impl(a, b, c, 0);
}

__device__ inline bool is_bf16_inputs(const void* sadj) {
  return ((*(const uint32_t*)sadj) & 0xFFFFu) == 0x3F80u;
}
__device__ inline float ldval(const void* p, size_t i, bool isbf) {
  if (isbf) return __bfloat162float(((const __hip_bfloat16*)p)[i]);
  return ((const float*)p)[i];
}
__device__ inline uint16_t f2bf_bits(float f) {
  __hip_bfloat16 h = __float2bfloat16(f);
  return *(uint16_t*)&h;
}
__device__ inline float bf2f(uint16_t u) {
  uint32_t i = ((uint32_t)u) << 16;
  return __builtin_bit_cast(float, i);
}

// ---- workspace layout (bytes) ----
static constexpr size_t OFF_ADJ = 0;                                   // int [2][4096][128]
static constexpr size_t OFF_DEG = OFF_ADJ + (size_t)2 * 4096 * MAXDEG * 4;
static constexpr size_t OFF_XB  = OFF_DEG + (size_t)2 * 4096 * 4;      // bf16 [4096][256]
static constexpr size_t OFF_WT  = OFF_XB  + (size_t)4096 * 256 * 2;    // bf16 [2][4][64][256]
static constexpr size_t OFF_WOT = OFF_WT  + (size_t)2 * 4 * 64 * 256 * 2; // bf16 [2][64][256]
static constexpr size_t OFF_AV  = OFF_WOT + (size_t)2 * 64 * 256 * 2;  // f32 [2][4][128]
static constexpr size_t OFF_AOV = OFF_AV  + (size_t)2 * 4 * 128 * 4;   // f32 [2][128]
static constexpr size_t OFF_WP1 = OFF_AOV + (size_t)2 * 128 * 4;       // f32 [64][16]
static constexpr size_t OFF_BP1 = OFF_WP1 + (size_t)64 * 16 * 4;       // f32 [16]
static constexpr size_t OFF_WP2 = OFF_BP1 + 64;                        // f32 [16]
static constexpr size_t OFF_WH1B = OFF_WP2 + 192;                      // bf16 [2][4096][256]
static constexpr size_t OFF_S1  = OFF_WH1B + (size_t)2 * 4096 * 256 * 2; // f32 [2][4096][4]
static constexpr size_t OFF_D1  = OFF_S1  + (size_t)2 * 4 * 4096 * 4;    // f32 [2][4096][4]
static constexpr size_t OFF_H2  = OFF_D1  + (size_t)2 * 4 * 4096 * 4;  // bf16 [2][4096][256]
static constexpr size_t OFF_WH2B = OFF_H2 + (size_t)2 * 4096 * 256 * 2; // bf16 [2][4096][64]
static constexpr size_t OFF_S2  = OFF_WH2B + (size_t)2 * 4096 * 64 * 2; // f32 [2][4096]
static constexpr size_t OFF_D2  = OFF_S2  + (size_t)2 * 4096 * 4;
static constexpr size_t OFF_M0  = OFF_D2  + (size_t)2 * 4096 * 4;      // bf16 copy of sadj (33.5MB)

// ---------------------------------------------------------------------------
// k_pre: blocks [0,1024) = x->bf16 ; [1024,1680) = W transpose + smalls
__global__ __launch_bounds__(256) void k_pre(const void* x,
    const void* W1, const void* W2, const void* Wo1, const void* Wo2,
    const void* a1, const void* a2, const void* ao1, const void* ao2,
    const void* wp1, const void* bp1, const void* wp2, const void* sadj,
    uint16_t* xb, uint16_t* Wt, uint16_t* Wot,
    float* Av, float* Aov, float* Wp1v, float* Bp1v, float* Wp2v) {
  bool isbf = is_bf16_inputs(sadj);
  int bid = blockIdx.x;
  if (bid < 1024) {
    int i0 = (bid * 256 + threadIdx.x) * 4;
    if (isbf) {
      *(uint64_t*)(xb + i0) = *(const uint64_t*)((const uint16_t*)x + i0);
    } else {
      const float* xf = (const float*)x;
      float4 f = *(const float4*)(xf + i0);
      xb[i0 + 0] = f2bf_bits(f.x);
      xb[i0 + 1] = f2bf_bits(f.y);
      xb[i0 + 2] = f2bf_bits(f.z);
      xb[i0 + 3] = f2bf_bits(f.w);
    }
    return;
  }
  int idx = (bid - 1024) * 256 + threadIdx.x;  // 656 blocks
  if (idx < 131072) {
    int k = idx & 255, f = (idx >> 8) & 63, h = (idx >> 14) & 3, g = idx >> 16;
    const void* W = g ? W2 : W1;
    Wt[idx] = f2bf_bits(ldval(W, (size_t)h * 16384 + (size_t)k * 64 + f, isbf));
  } else if (idx < 163840) {
    int j = idx - 131072;
    int k = j & 255, f = (j >> 8) & 63, g = j >> 14;
    const void* W = g ? Wo2 : Wo1;
    Wot[j] = f2bf_bits(ldval(W, (size_t)k * 64 + f, isbf));
  } else if (idx < 166176) {
    int q = idx - 163840;  // [0, 2336)
    if (q < 512)        Av[q] = ldval(a1, q, isbf);
    else if (q < 1024)  Av[q] = ldval(a2, q - 512, isbf);
    else if (q < 1152)  Aov[q - 1024] = ldval(ao1, q - 1024, isbf);
    else if (q < 1280)  Aov[q - 1152 + 128] = ldval(ao2, q - 1152, isbf);
    else if (q < 2304)  Wp1v[q - 1280] = ldval(wp1, q - 1280, isbf);
    else if (q < 2320)  Bp1v[q - 2304] = ldval(bp1, q - 2304, isbf);
    else                Wp2v[q - 2320] = ldval(wp2, q - 2320, isbf);
  }
}

// one-pass adjacency build: block = one row (8KB bf16). thread t covers cols
// [16t,16t+16) -> 16-bit hit mask; wave shuffle-scan + LDS cross-wave scan;
// ordered scatter. Deterministic, sorted, no atomics.
__device__ inline void adj_row(const uint16_t* mrow_bf, const float* mrow_f32,
                               bool isbf, int gn, int* adj, int* deg) {
  __shared__ int wtot[4];
  int t = threadIdx.x;
  uint32_t bits = 0;
  if (isbf) {
    uintx4 v0 = *((const uintx4*)mrow_bf + 2 * t);
    uintx4 v1 = *((const uintx4*)mrow_bf + 2 * t + 1);
    uint32_t wd[8] = {v0.x, v0.y, v0.z, v0.w, v1.x, v1.y, v1.z, v1.w};
#pragma unroll
    for (int k = 0; k < 16; ++k) {
      uint16_t val = (uint16_t)(wd[k >> 1] >> ((k & 1) * 16));
      if (val != 0 && !(val & 0x8000)) bits |= 1u << k;
    }
  } else {
#pragma unroll
    for (int j = 0; j < 4; ++j) {
      floatx4 v = *((const floatx4*)mrow_f32 + 4 * t + j);
      if (v.x > 0.f) bits |= 1u << (4 * j + 0);
      if (v.y > 0.f) bits |= 1u << (4 * j + 1);
      if (v.z > 0.f) bits |= 1u << (4 * j + 2);
      if (v.w > 0.f) bits |= 1u << (4 * j + 3);
    }
  }
  int c = __popc(bits);
  int lane = t & 63, wid = t >> 6;
  int pre = c;
#pragma unroll
  for (int o = 1; o < 64; o <<= 1) {
    int tv = __shfl_up(pre, o);
    if (lane >= o) pre += tv;
  }
  if (lane == 63) wtot[wid] = pre;
  __syncthreads();
  int base = 0, total = 0;
#pragma unroll
  for (int wq = 0; wq < 4; ++wq) {
    int v = wtot[wq];
    if (wq < wid) base += v;
    total += v;
  }
  int off = base + pre - c;
  int colbase = t * 16;
  int* out = adj + (size_t)gn * MAXDEG;
  while (bits) {
    int i = __ffs(bits) - 1;
    bits &= bits - 1;
    if (off < MAXDEG) out[off] = colbase + i;
    ++off;
  }
  if (t == 0) deg[gn] = total < MAXDEG ? total : MAXDEG;
}

// graph 0: reads the SDMA ws copy (bf16 path) / sadj directly (fp32 hedge)
__global__ __launch_bounds__(256) void k_adjA(const uint16_t* m0ws, const void* sadj,
                                              int* adj, int* deg) {
  bool isbf = is_bf16_inputs(sadj);
  int row = blockIdx.x;
  adj_row(m0ws + (size_t)row * 4096,
          (const float*)sadj + (size_t)row * 4096, isbf, row, adj, deg);
}

// graph 1: reads d_in directly -- the A/B control
__global__ __launch_bounds__(256) void k_adjB(const void* sadj2,
                                              int* adj, int* deg) {
  bool isbf = is_bf16_inputs(sadj2);
  int row = blockIdx.x;
  adj_row((const uint16_t*)sadj2 + (size_t)row * 4096,
          (const float*)sadj2 + (size_t)row * 4096, isbf, 4096 + row, adj, deg);
}

// GEMM1 + fused sd1 epilogue. Wh1b bf16 out.
__global__ __launch_bounds__(256) void k_gemm1(const uint16_t* xb, const uint16_t* Wt,
                                               const float* Av,
                                               uint16_t* Wh1b, float* s1, float* d1) {
  int w = blockIdx.x * 4 + (threadIdx.x >> 6);  // [0, 2048)
  int lane = threadIdx.x & 63;
  int q = lane >> 4, c = lane & 15;
  int g = w >> 10, rem = w & 1023;
  int m0 = (rem >> 2) << 4, h = rem & 3;
  const uint16_t* B = Wt + (size_t)(g * 4 + h) * 64 * 256;
  floatx4 acc[4] = {};
  const uint16_t* arow = xb + (size_t)(m0 + c) * 256 + q * 8;
  for (int kk = 0; kk < 8; ++kk) {
    short8 a = *(const short8*)(arow + kk * 32);
#pragma unroll
    for (int t = 0; t < 4; ++t) {
      short8 b = *(const short8*)(B + (size_t)(t * 16 + c) * 256 + kk * 32 + q * 8);
      acc[t] = MFMA16(a, b, acc[t]);
    }
  }
  uint16_t* Crow = Wh1b + (size_t)(g * 4096 + m0) * 256 + h * 64;
#pragma unroll
  for (int t = 0; t < 4; ++t)
#pragma unroll
    for (int r = 0; r < 4; ++r)
      Crow[(size_t)(q * 4 + r) * 256 + t * 16 + c] = f2bf_bits(acc[t][r]);
  const float* ag = Av + (g * 4 + h) * 128;
  float as[4], ad[4];
#pragma unroll
  for (int t = 0; t < 4; ++t) { as[t] = ag[t * 16 + c]; ad[t] = ag[64 + t * 16 + c]; }
#pragma unroll
  for (int r = 0; r < 4; ++r) {
    float ps = 0.f, pd = 0.f;
#pragma unroll
    for (int t = 0; t < 4; ++t) { ps += acc[t][r] * as[t]; pd += acc[t][r] * ad[t]; }
#pragma unroll
    for (int o = 1; o < 16; o <<= 1) { ps += __shfl_xor(ps, o); pd += __shfl_xor(pd, o); }
    if (c == 0) {
      int n = m0 + q * 4 + r;
      s1[((size_t)(g * 4096 + n)) * 4 + h] = ps;
      d1[((size_t)(g * 4096 + n)) * 4 + h] = pd;
    }
  }
}

// sparse attention layer1 + elu -> h2 (bf16). wave per (g,n); all 4 heads.
__global__ __launch_bounds__(256) void k_att1(const int* adj, const int* deg,
    const float* s1, const float* d1, const uint16_t* Wh1b, uint16_t* h2) {
  __shared__ float pbuf[4][4][MAXDEG];
  __shared__ int jbuf[4][MAXDEG];
  int wv = threadIdx.x >> 6, lane = threadIdx.x & 63;
  int w = blockIdx.x * 4 + wv;  // [0, 8192)
  int g = w >> 12;
  int gn = w;
  int dg = deg[gn];
  const int* nbr = adj + (size_t)gn * MAXDEG;
  float4 s4 = *(const float4*)(s1 + (size_t)gn * 4);
  const float4* d4 = (const float4*)(d1) + (size_t)g * 4096;

  bool v0 = lane < dg, v1 = lane + 64 < dg;
  int j0 = 0, j1 = 0;
  if (v0) j0 = nbr[lane];
  if (v1) j1 = nbr[lane + 64];
  float4 dj0 = d4[j0];
  float4 dj1 = d4[j1];
  if (v0) jbuf[wv][lane] = j0;
  if (v1) jbuf[wv][lane + 64] = j1;

  const float ninf = -3.0e38f;
  float sa[4] = {s4.x, s4.y, s4.z, s4.w};
  float d0a[4] = {dj0.x, dj0.y, dj0.z, dj0.w};
  float d1a[4] = {dj1.x, dj1.y, dj1.z, dj1.w};
#pragma unroll
  for (int h = 0; h < 4; ++h) {
    float t0 = sa[h] + d0a[h]; t0 = t0 > 0.f ? t0 : LRELU * t0;
    float t1 = sa[h] + d1a[h]; t1 = t1 > 0.f ? t1 : LRELU * t1;
    float e0 = v0 ? t0 : ninf;
    float e1 = v1 ? t1 : ninf;
    float m = fmaxf(e0, e1);
#pragma unroll
    for (int o = 32; o; o >>= 1) m = fmaxf(m, __shfl_xor(m, o));
    float p0 = v0 ? __expf(e0 - m) : 0.f;
    float p1 = v1 ? __expf(e1 - m) : 0.f;
    float l = p0 + p1;
#pragma unroll
    for (int o = 32; o; o >>= 1) l += __shfl_xor(l, o);
    float inv = __frcp_rn(l);
    pbuf[wv][h][lane] = p0 * inv;
    pbuf[wv][h][lane + 64] = p1 * inv;
  }
  int myh = lane >> 4;
  const float* prow = pbuf[wv][myh];
  const int* jb = jbuf[wv];
  const uint16_t* Wg = Wh1b + (size_t)g * 4096 * 256;
  float ax = 0.f, ay = 0.f, az = 0.f, aw = 0.f;
  for (int i = 0; i < dg; i += 8) {
    float pv[8];
    ushort4 wv8[8];
#pragma unroll
    for (int k = 0; k < 8; ++k) {
      int idx = i + k;
      bool vv = idx < dg;
      int sidx = vv ? idx : 0;
      int j = jb[sidx];
      pv[k] = vv ? prow[sidx] : 0.f;
      wv8[k] = *(const ushort4*)(Wg + (size_t)j * 256 + lane * 4);
    }
#pragma unroll
    for (int k = 0; k < 8; ++k) {
      ax += pv[k] * bf2f(wv8[k].x);
      ay += pv[k] * bf2f(wv8[k].y);
      az += pv[k] * bf2f(wv8[k].z);
      aw += pv[k] * bf2f(wv8[k].w);
    }
  }
  ax = ax > 0.f ? ax : __expf(ax) - 1.f;
  ay = ay > 0.f ? ay : __expf(ay) - 1.f;
  az = az > 0.f ? az : __expf(az) - 1.f;
  aw = aw > 0.f ? aw : __expf(aw) - 1.f;
  ushort4 o4 = {f2bf_bits(ax), f2bf_bits(ay), f2bf_bits(az), f2bf_bits(aw)};
  *(ushort4*)(h2 + (size_t)gn * 256 + lane * 4) = o4;
}

// GEMM2 + fused sd2 epilogue; Wh2b bf16 out.
__global__ __launch_bounds__(256) void k_gemm2(const uint16_t* h2, const uint16_t* Wot,
                                               const float* Aov,
                                               uint16_t* Wh2b, float* s2, float* d2) {
  int w = blockIdx.x * 4 + (threadIdx.x >> 6);  // [0, 512)
  int lane = threadIdx.x & 63;
  int q = lane >> 4, c = lane & 15;
  int g = w >> 8, m0 = (w & 255) << 4;
  const uint16_t* A = h2 + (size_t)g * 4096 * 256;
  const uint16_t* B = Wot + (size_t)g * 64 * 256;
  floatx4 acc[4] = {};
  const uint16_t* arow = A + (size_t)(m0 + c) * 256 + q * 8;
  for (int kk = 0; kk < 8; ++kk) {
    short8 a = *(const short8*)(arow + kk * 32);
#pragma unroll
    for (int t = 0; t < 4; ++t) {
      short8 b = *(const short8*)(B + (size_t)(t * 16 + c) * 256 + kk * 32 + q * 8);
      acc[t] = MFMA16(a, b, acc[t]);
    }
  }
  uint16_t* Crow = Wh2b + (size_t)(g * 4096 + m0) * 64;
#pragma unroll
  for (int t = 0; t < 4; ++t)
#pragma unroll
    for (int r = 0; r < 4; ++r)
      Crow[(size_t)(q * 4 + r) * 64 + t * 16 + c] = f2bf_bits(acc[t][r]);
  const float* ag = Aov + g * 128;
  float as[4], ad[4];
#pragma unroll
  for (int t = 0; t < 4; ++t) { as[t] = ag[t * 16 + c]; ad[t] = ag[64 + t * 16 + c]; }
#pragma unroll
  for (int r = 0; r < 4; ++r) {
    float ps = 0.f, pd = 0.f;
#pragma unroll
    for (int t = 0; t < 4; ++t) { ps += acc[t][r] * as[t]; pd += acc[t][r] * ad[t]; }
#pragma unroll
    for (int o = 1; o < 16; o <<= 1) { ps += __shfl_xor(ps, o); pd += __shfl_xor(pd, o); }
    if (c == 0) {
      int n = m0 + q * 4 + r;
      s2[g * 4096 + n] = ps;
      d2[g * 4096 + n] = pd;
    }
  }
}

// att2 + semantic-attention final, fused. Block = 2 nodes x 2 graphs.
__global__ __launch_bounds__(256) void k_att2f(const int* adj, const int* deg,
    const float* s2, const float* d2, const uint16_t* Wh2b,
    const float* Wp1v, const float* Bp1v, const float* Wp2v,
    const void* sadj, void* out) {
  __shared__ float pbuf[4][MAXDEG];
  __shared__ int jbuf[4][MAXDEG];
  __shared__ float emb_s[4][64];
  __shared__ float st_s[2][32];
  __shared__ float sw_s[2][2];
  int wv = threadIdx.x >> 6, lane = threadIdx.x & 63;
  int g = wv >> 1, nl = wv & 1;
  int n = blockIdx.x * 2 + nl;
  int gn = g * 4096 + n;
  int dg = deg[gn];
  const int* nbr = adj + (size_t)gn * MAXDEG;
  float sn = s2[gn];
  const float* dp = d2 + (size_t)g * 4096;

  bool v0 = lane < dg, v1 = lane + 64 < dg;
  int j0 = 0, j1 = 0;
  if (v0) j0 = nbr[lane];
  if (v1) j1 = nbr[lane + 64];
  float dd0 = dp[j0], dd1 = dp[j1];
  if (v0) jbuf[wv][lane] = j0;
  if (v1) jbuf[wv][lane + 64] = j1;

  const float ninf = -3.0e38f;
  float t0 = sn + dd0; t0 = t0 > 0.f ? t0 : LRELU * t0;
  float t1 = sn + dd1; t1 = t1 > 0.f ? t1 : LRELU * t1;
  float e0 = v0 ? t0 : ninf;
  float e1 = v1 ? t1 : ninf;
  float m = fmaxf(e0, e1);
#pragma unroll
  for (int o = 32; o; o >>= 1) m = fmaxf(m, __shfl_xor(m, o));
  float p0 = v0 ? __expf(e0 - m) : 0.f;
  float p1 = v1 ? __expf(e1 - m) : 0.f;
  float l = p0 + p1;
#pragma unroll
  for (int o = 32; o; o >>= 1) l += __shfl_xor(l, o);
  float inv = __frcp_rn(l);
  pbuf[wv][lane] = p0 * inv;
  pbuf[wv][lane + 64] = p1 * inv;

  int mye = lane >> 4, c4 = lane & 15;
  const uint16_t* Wg = Wh2b + (size_t)g * 4096 * 64;
  float ax = 0.f, ay = 0.f, az = 0.f, aw = 0.f;
  for (int i = 0; i < dg; i += 8) {
    int ia = i + mye, ib = i + 4 + mye;
    bool va = ia < dg, vb = ib < dg;
    int sa_ = va ? ia : 0, sb_ = vb ? ib : 0;
    int ja = jbuf[wv][sa_], jb2 = jbuf[wv][sb_];
    float pa = va ? pbuf[wv][sa_] : 0.f;
    float pb = vb ? pbuf[wv][sb_] : 0.f;
    ushort4 wa = *(const ushort4*)(Wg + (size_t)ja * 64 + c4 * 4);
    ushort4 wb = *(const ushort4*)(Wg + (size_t)jb2 * 64 + c4 * 4);
    ax += pa * bf2f(wa.x) + pb * bf2f(wb.x);
    ay += pa * bf2f(wa.y) + pb * bf2f(wb.y);
    az += pa * bf2f(wa.z) + pb * bf2f(wb.z);
    aw += pa * bf2f(wa.w) + pb * bf2f(wb.w);
  }
#pragma unroll
  for (int o = 16; o <= 32; o <<= 1) {
    ax += __shfl_xor(ax, o);
    ay += __shfl_xor(ay, o);
    az += __shfl_xor(az, o);
    aw += __shfl_xor(aw, o);
  }
  if (lane < 16) {
    ax = ax > 0.f ? ax : __expf(ax) - 1.f;
    ay = ay > 0.f ? ay : __expf(ay) - 1.f;
    az = az > 0.f ? az : __expf(az) - 1.f;
    aw = aw > 0.f ? aw : __expf(aw) - 1.f;
    float4 r = {ax, ay, az, aw};
    *(float4*)&emb_s[wv][c4 * 4] = r;
  }
  __syncthreads();
  if (wv < 2) {
    float e1v = emb_s[wv][lane];       // g=0
    float e2v = emb_s[2 + wv][lane];   // g=1
    if (lane < 32) {
      int gg = lane >> 4, p = lane & 15;
      float s = Bp1v[p];
      const float* eb = emb_s[gg * 2 + wv];
      for (int f = 0; f < 64; ++f) s += eb[f] * Wp1v[f * 16 + p];
      st_s[wv][lane] = tanhf(s);
    }
    if (lane < 2) {
      float s = 0.f;
      for (int p = 0; p < 16; ++p) s += st_s[wv][lane * 16 + p] * Wp2v[p];
      sw_s[wv][lane] = s;
    }
    float w0 = sw_s[wv][0], w1 = sw_s[wv][1];
    float mx = fmaxf(w0, w1);
    float q0 = __expf(w0 - mx), q1 = __expf(w1 - mx);
    float qi = 1.f / (q0 + q1);
    float v = (q0 * e1v + q1 * e2v) * qi;
    if (is_bf16_inputs(sadj)) ((uint16_t*)out)[(size_t)n * 64 + lane] = f2bf_bits(v);
    else ((float*)out)[(size_t)n * 64 + lane] = v;
  }
}

// ---------------------------------------------------------------------------
extern "C" void kernel_launch(void* const* d_in, const int* in_sizes, int n_in,
                              void* d_out, int out_size, void* d_ws, size_t ws_size,
                              hipStream_t stream) {
  const void* x    = d_in[0];
  const void* sadj = d_in[1];
  const void* sadj2 = d_in[2];
  const void* W1  = d_in[3];
  const void* a1  = d_in[4];
  const void* Wo1 = d_in[5];
  const void* ao1 = d_in[6];
  const void* W2  = d_in[7];
  const void* a2  = d_in[8];
  const void* Wo2 = d_in[9];
  const void* ao2 = d_in[10];
  const void* Wp1 = d_in[11];
  const void* bp1 = d_in[12];
  const void* Wp2 = d_in[13];

  char* ws = (char*)d_ws;
  int* adj      = (int*)(ws + OFF_ADJ);
  int* deg      = (int*)(ws + OFF_DEG);
  uint16_t* xb  = (uint16_t*)(ws + OFF_XB);
  uint16_t* Wt  = (uint16_t*)(ws + OFF_WT);
  uint16_t* Wot = (uint16_t*)(ws + OFF_WOT);
  float* Av     = (float*)(ws + OFF_AV);
  float* Aov    = (float*)(ws + OFF_AOV);
  float* Wp1v   = (float*)(ws + OFF_WP1);
  float* Bp1v   = (float*)(ws + OFF_BP1);
  float* Wp2v   = (float*)(ws + OFF_WP2);
  uint16_t* Wh1b = (uint16_t*)(ws + OFF_WH1B);
  float* s1     = (float*)(ws + OFF_S1);
  float* d1     = (float*)(ws + OFF_D1);
  uint16_t* h2  = (uint16_t*)(ws + OFF_H2);
  uint16_t* Wh2b = (uint16_t*)(ws + OFF_WH2B);
  float* s2     = (float*)(ws + OFF_S2);
  float* d2     = (float*)(ws + OFF_D2);
  uint16_t* m0  = (uint16_t*)(ws + OFF_M0);

  // A/B probe: SDMA-copy sadj (bf16 size) into ws; k_adjA reads the copy,
  // k_adjB reads d_in directly with identical code.
  hipMemcpyAsync(m0, sadj, (size_t)4096 * 4096 * 2, hipMemcpyDeviceToDevice,
                 stream);
  k_pre<<<1680, 256, 0, stream>>>(x, W1, W2, Wo1, Wo2, a1, a2, ao1, ao2,
                                  Wp1, bp1, Wp2, sadj,
                                  xb, Wt, Wot, Av, Aov, Wp1v, Bp1v, Wp2v);
  k_adjA<<<4096, 256, 0, stream>>>(m0, sadj, adj, deg);
  k_adjB<<<4096, 256, 0, stream>>>(sadj2, adj, deg);
  k_gemm1<<<512, 256, 0, stream>>>(xb, Wt, Av, Wh1b, s1, d1);
  k_att1<<<2048, 256, 0, stream>>>(adj, deg, s1, d1, Wh1b, h2);
  k_gemm2<<<128, 256, 0, stream>>>(h2, Wot, Aov, Wh2b, s2, d2);
  k_att2f<<<2048, 256, 0, stream>>>(adj, deg, s2, d2, Wh2b,
                                    Wp1v, Bp1v, Wp2v, sadj, d_out);
}

// Round 8
// 218.379 us; speedup vs baseline: 1.0770x; 1.0770x over previous
//
#include <hip/hip_runtime.h>
#include <hip/hip_bf16.h>
#include <stdint.h>

// ---------------------------------------------------------------------------
// U_GCN: 2x (4-head GAT layer -> 1-head GAT out layer) + semantic attention.
// N=4096, Fin=256, H=4, Fh=64, Ff=64, P=16. Masks ~0.5% dense + diagonal.
// R8: single fused front kernel (adj build for both graphs, one-pass
// block-per-row, direct from d_in + all dtype conversions), then
// gemm1 -> att1 -> gemm2 -> att2f. 5 launches, no memcpy, no bitmap.
// Known environment fact: the harness's 268MB d_ws poison fill overlaps the
// first kernel and eats ~6.5 TB/s of HBM; first kernel sees ~1.5 TB/s.
// ---------------------------------------------------------------------------

typedef short short8 __attribute__((ext_vector_type(8)));
typedef __bf16 bf16x8 __attribute__((ext_vector_type(8)));
typedef float floatx4 __attribute__((ext_vector_type(4)));
typedef unsigned int uintx4 __attribute__((ext_vector_type(4)));

#define MAXDEG 128
#define LRELU 0.2f

template <typename V>
__device__ inline auto mfma_impl(V a, V b, floatx4 c, int)
    -> decltype(__builtin_amdgcn_mfma_f32_16x16x32_bf16(a, b, c, 0, 0, 0)) {
  return __builtin_amdgcn_mfma_f32_16x16x32_bf16(a, b, c, 0, 0, 0);
}
template <typename V>
__device__ inline floatx4 mfma_impl(V a, V b, floatx4 c, long) {
  return __builtin_amdgcn_mfma_f32_16x16x32_bf16(
      __builtin_bit_cast(bf16x8, a), __builtin_bit_cast(bf16x8, b), c, 0, 0, 0);
}
__device__ inline floatx4 MFMA16(short8 a, short8 b, floatx4 c) {
  return mfma_impl(a, b, c, 0);
}

__device__ inline bool is_bf16_inputs(const void* sadj) {
  return ((*(const uint32_t*)sadj) & 0xFFFFu) == 0x3F80u;
}
__device__ inline float ldval(const void* p, size_t i, bool isbf) {
  if (isbf) return __bfloat162float(((const __hip_bfloat16*)p)[i]);
  return ((const float*)p)[i];
}
__device__ inline uint16_t f2bf_bits(float f) {
  __hip_bfloat16 h = __float2bfloat16(f);
  return *(uint16_t*)&h;
}
__device__ inline float bf2f(uint16_t u) {
  uint32_t i = ((uint32_t)u) << 16;
  return __builtin_bit_cast(float, i);
}

// ---- workspace layout (bytes) ----
static constexpr size_t OFF_ADJ = 0;                                   // int [2][4096][128]
static constexpr size_t OFF_DEG = OFF_ADJ + (size_t)2 * 4096 * MAXDEG * 4;
static constexpr size_t OFF_XB  = OFF_DEG + (size_t)2 * 4096 * 4;      // bf16 [4096][256]
static constexpr size_t OFF_WT  = OFF_XB  + (size_t)4096 * 256 * 2;    // bf16 [2][4][64][256]
static constexpr size_t OFF_WOT = OFF_WT  + (size_t)2 * 4 * 64 * 256 * 2; // bf16 [2][64][256]
static constexpr size_t OFF_AV  = OFF_WOT + (size_t)2 * 64 * 256 * 2;  // f32 [2][4][128]
static constexpr size_t OFF_AOV = OFF_AV  + (size_t)2 * 4 * 128 * 4;   // f32 [2][128]
static constexpr size_t OFF_WP1 = OFF_AOV + (size_t)2 * 128 * 4;       // f32 [64][16]
static constexpr size_t OFF_BP1 = OFF_WP1 + (size_t)64 * 16 * 4;       // f32 [16]
static constexpr size_t OFF_WP2 = OFF_BP1 + 64;                        // f32 [16]
static constexpr size_t OFF_WH1B = OFF_WP2 + 192;                      // bf16 [2][4096][256]
static constexpr size_t OFF_S1  = OFF_WH1B + (size_t)2 * 4096 * 256 * 2; // f32 [2][4096][4]
static constexpr size_t OFF_D1  = OFF_S1  + (size_t)2 * 4 * 4096 * 4;    // f32 [2][4096][4]
static constexpr size_t OFF_H2  = OFF_D1  + (size_t)2 * 4 * 4096 * 4;  // bf16 [2][4096][256]
static constexpr size_t OFF_WH2B = OFF_H2 + (size_t)2 * 4096 * 256 * 2; // bf16 [2][4096][64]
static constexpr size_t OFF_S2  = OFF_WH2B + (size_t)2 * 4096 * 64 * 2; // f32 [2][4096]
static constexpr size_t OFF_D2  = OFF_S2  + (size_t)2 * 4096 * 4;

// ---------------------------------------------------------------------------
// one-pass adjacency build for one row: 256 threads, thread t covers cols
// [16t,16t+16) -> 16-bit hit mask; wave shuffle-scan + LDS cross-wave scan;
// ordered scatter. Deterministic, sorted, no atomics. (verified R7)
__device__ inline void adj_row(const uint16_t* mrow_bf, const float* mrow_f32,
                               bool isbf, int gn, int* adj, int* deg) {
  __shared__ int wtot[4];
  int t = threadIdx.x;
  uint32_t bits = 0;
  if (isbf) {
    uintx4 v0 = *((const uintx4*)mrow_bf + 2 * t);
    uintx4 v1 = *((const uintx4*)mrow_bf + 2 * t + 1);
    uint32_t wd[8] = {v0.x, v0.y, v0.z, v0.w, v1.x, v1.y, v1.z, v1.w};
#pragma unroll
    for (int k = 0; k < 16; ++k) {
      uint16_t val = (uint16_t)(wd[k >> 1] >> ((k & 1) * 16));
      if (val != 0 && !(val & 0x8000)) bits |= 1u << k;
    }
  } else {
#pragma unroll
    for (int j = 0; j < 4; ++j) {
      floatx4 v = *((const floatx4*)mrow_f32 + 4 * t + j);
      if (v.x > 0.f) bits |= 1u << (4 * j + 0);
      if (v.y > 0.f) bits |= 1u << (4 * j + 1);
      if (v.z > 0.f) bits |= 1u << (4 * j + 2);
      if (v.w > 0.f) bits |= 1u << (4 * j + 3);
    }
  }
  int c = __popc(bits);
  int lane = t & 63, wid = t >> 6;
  int pre = c;
#pragma unroll
  for (int o = 1; o < 64; o <<= 1) {
    int tv = __shfl_up(pre, o);
    if (lane >= o) pre += tv;
  }
  if (lane == 63) wtot[wid] = pre;
  __syncthreads();
  int base = 0, total = 0;
#pragma unroll
  for (int wq = 0; wq < 4; ++wq) {
    int v = wtot[wq];
    if (wq < wid) base += v;
    total += v;
  }
  int off = base + pre - c;
  int colbase = t * 16;
  int* out = adj + (size_t)gn * MAXDEG;
  while (bits) {
    int i = __ffs(bits) - 1;
    bits &= bits - 1;
    if (off < MAXDEG) out[off] = colbase + i;
    ++off;
  }
  if (t == 0) deg[gn] = total < MAXDEG ? total : MAXDEG;
}

// k_pre_adj: blocks [0,8192) = adj build (both graphs, direct from d_in);
//            [8192,9216) = x->bf16 ; [9216,9872) = W transpose + smalls
__global__ __launch_bounds__(256) void k_pre_adj(
    const void* sadj, const void* sadj2, const void* x,
    const void* W1, const void* W2, const void* Wo1, const void* Wo2,
    const void* a1, const void* a2, const void* ao1, const void* ao2,
    const void* wp1, const void* bp1, const void* wp2,
    int* adj, int* deg, uint16_t* xb, uint16_t* Wt, uint16_t* Wot,
    float* Av, float* Aov, float* Wp1v, float* Bp1v, float* Wp2v) {
  bool isbf = is_bf16_inputs(sadj);
  int bid = blockIdx.x;
  if (bid < 8192) {
    int g = bid >> 12, n = bid & 4095;
    const void* mask = g ? sadj2 : sadj;
    adj_row((const uint16_t*)mask + (size_t)n * 4096,
            (const float*)mask + (size_t)n * 4096, isbf, bid, adj, deg);
    return;
  }
  if (bid < 9216) {
    int i0 = ((bid - 8192) * 256 + threadIdx.x) * 4;
    if (isbf) {
      *(uint64_t*)(xb + i0) = *(const uint64_t*)((const uint16_t*)x + i0);
    } else {
      const float* xf = (const float*)x;
      float4 f = *(const float4*)(xf + i0);
      xb[i0 + 0] = f2bf_bits(f.x);
      xb[i0 + 1] = f2bf_bits(f.y);
      xb[i0 + 2] = f2bf_bits(f.z);
      xb[i0 + 3] = f2bf_bits(f.w);
    }
    return;
  }
  int idx = (bid - 9216) * 256 + threadIdx.x;  // 656 blocks
  if (idx < 131072) {
    int k = idx & 255, f = (idx >> 8) & 63, h = (idx >> 14) & 3, g = idx >> 16;
    const void* W = g ? W2 : W1;
    Wt[idx] = f2bf_bits(ldval(W, (size_t)h * 16384 + (size_t)k * 64 + f, isbf));
  } else if (idx < 163840) {
    int j = idx - 131072;
    int k = j & 255, f = (j >> 8) & 63, g = j >> 14;
    const void* W = g ? Wo2 : Wo1;
    Wot[j] = f2bf_bits(ldval(W, (size_t)k * 64 + f, isbf));
  } else if (idx < 166176) {
    int q = idx - 163840;  // [0, 2336)
    if (q < 512)        Av[q] = ldval(a1, q, isbf);
    else if (q < 1024)  Av[q] = ldval(a2, q - 512, isbf);
    else if (q < 1152)  Aov[q - 1024] = ldval(ao1, q - 1024, isbf);
    else if (q < 1280)  Aov[q - 1152 + 128] = ldval(ao2, q - 1152, isbf);
    else if (q < 2304)  Wp1v[q - 1280] = ldval(wp1, q - 1280, isbf);
    else if (q < 2320)  Bp1v[q - 2304] = ldval(bp1, q - 2304, isbf);
    else                Wp2v[q - 2320] = ldval(wp2, q - 2320, isbf);
  }
}

// GEMM1 + fused sd1 epilogue. Wh1b bf16 out.
__global__ __launch_bounds__(256) void k_gemm1(const uint16_t* xb, const uint16_t* Wt,
                                               const float* Av,
                                               uint16_t* Wh1b, float* s1, float* d1) {
  int w = blockIdx.x * 4 + (threadIdx.x >> 6);  // [0, 2048)
  int lane = threadIdx.x & 63;
  int q = lane >> 4, c = lane & 15;
  int g = w >> 10, rem = w & 1023;
  int m0 = (rem >> 2) << 4, h = rem & 3;
  const uint16_t* B = Wt + (size_t)(g * 4 + h) * 64 * 256;
  floatx4 acc[4] = {};
  const uint16_t* arow = xb + (size_t)(m0 + c) * 256 + q * 8;
  for (int kk = 0; kk < 8; ++kk) {
    short8 a = *(const short8*)(arow + kk * 32);
#pragma unroll
    for (int t = 0; t < 4; ++t) {
      short8 b = *(const short8*)(B + (size_t)(t * 16 + c) * 256 + kk * 32 + q * 8);
      acc[t] = MFMA16(a, b, acc[t]);
    }
  }
  uint16_t* Crow = Wh1b + (size_t)(g * 4096 + m0) * 256 + h * 64;
#pragma unroll
  for (int t = 0; t < 4; ++t)
#pragma unroll
    for (int r = 0; r < 4; ++r)
      Crow[(size_t)(q * 4 + r) * 256 + t * 16 + c] = f2bf_bits(acc[t][r]);
  const float* ag = Av + (g * 4 + h) * 128;
  float as[4], ad[4];
#pragma unroll
  for (int t = 0; t < 4; ++t) { as[t] = ag[t * 16 + c]; ad[t] = ag[64 + t * 16 + c]; }
#pragma unroll
  for (int r = 0; r < 4; ++r) {
    float ps = 0.f, pd = 0.f;
#pragma unroll
    for (int t = 0; t < 4; ++t) { ps += acc[t][r] * as[t]; pd += acc[t][r] * ad[t]; }
#pragma unroll
    for (int o = 1; o < 16; o <<= 1) { ps += __shfl_xor(ps, o); pd += __shfl_xor(pd, o); }
    if (c == 0) {
      int n = m0 + q * 4 + r;
      s1[((size_t)(g * 4096 + n)) * 4 + h] = ps;
      d1[((size_t)(g * 4096 + n)) * 4 + h] = pd;
    }
  }
}

// sparse attention layer1 + elu -> h2 (bf16). wave per (g,n); all 4 heads.
__global__ __launch_bounds__(256) void k_att1(const int* adj, const int* deg,
    const float* s1, const float* d1, const uint16_t* Wh1b, uint16_t* h2) {
  __shared__ float pbuf[4][4][MAXDEG];
  __shared__ int jbuf[4][MAXDEG];
  int wv = threadIdx.x >> 6, lane = threadIdx.x & 63;
  int w = blockIdx.x * 4 + wv;  // [0, 8192)
  int g = w >> 12;
  int gn = w;
  int dg = deg[gn];
  const int* nbr = adj + (size_t)gn * MAXDEG;
  float4 s4 = *(const float4*)(s1 + (size_t)gn * 4);
  const float4* d4 = (const float4*)(d1) + (size_t)g * 4096;

  bool v0 = lane < dg, v1 = lane + 64 < dg;
  int j0 = 0, j1 = 0;
  if (v0) j0 = nbr[lane];
  if (v1) j1 = nbr[lane + 64];
  float4 dj0 = d4[j0];
  float4 dj1 = d4[j1];
  if (v0) jbuf[wv][lane] = j0;
  if (v1) jbuf[wv][lane + 64] = j1;

  const float ninf = -3.0e38f;
  float sa[4] = {s4.x, s4.y, s4.z, s4.w};
  float d0a[4] = {dj0.x, dj0.y, dj0.z, dj0.w};
  float d1a[4] = {dj1.x, dj1.y, dj1.z, dj1.w};
#pragma unroll
  for (int h = 0; h < 4; ++h) {
    float t0 = sa[h] + d0a[h]; t0 = t0 > 0.f ? t0 : LRELU * t0;
    float t1 = sa[h] + d1a[h]; t1 = t1 > 0.f ? t1 : LRELU * t1;
    float e0 = v0 ? t0 : ninf;
    float e1 = v1 ? t1 : ninf;
    float m = fmaxf(e0, e1);
#pragma unroll
    for (int o = 32; o; o >>= 1) m = fmaxf(m, __shfl_xor(m, o));
    float p0 = v0 ? __expf(e0 - m) : 0.f;
    float p1 = v1 ? __expf(e1 - m) : 0.f;
    float l = p0 + p1;
#pragma unroll
    for (int o = 32; o; o >>= 1) l += __shfl_xor(l, o);
    float inv = __frcp_rn(l);
    pbuf[wv][h][lane] = p0 * inv;
    pbuf[wv][h][lane + 64] = p1 * inv;
  }
  int myh = lane >> 4;
  const float* prow = pbuf[wv][myh];
  const int* jb = jbuf[wv];
  const uint16_t* Wg = Wh1b + (size_t)g * 4096 * 256;
  float ax = 0.f, ay = 0.f, az = 0.f, aw = 0.f;
  for (int i = 0; i < dg; i += 8) {
    float pv[8];
    ushort4 wv8[8];
#pragma unroll
    for (int k = 0; k < 8; ++k) {
      int idx = i + k;
      bool vv = idx < dg;
      int sidx = vv ? idx : 0;
      int j = jb[sidx];
      pv[k] = vv ? prow[sidx] : 0.f;
      wv8[k] = *(const ushort4*)(Wg + (size_t)j * 256 + lane * 4);
    }
#pragma unroll
    for (int k = 0; k < 8; ++k) {
      ax += pv[k] * bf2f(wv8[k].x);
      ay += pv[k] * bf2f(wv8[k].y);
      az += pv[k] * bf2f(wv8[k].z);
      aw += pv[k] * bf2f(wv8[k].w);
    }
  }
  ax = ax > 0.f ? ax : __expf(ax) - 1.f;
  ay = ay > 0.f ? ay : __expf(ay) - 1.f;
  az = az > 0.f ? az : __expf(az) - 1.f;
  aw = aw > 0.f ? aw : __expf(aw) - 1.f;
  ushort4 o4 = {f2bf_bits(ax), f2bf_bits(ay), f2bf_bits(az), f2bf_bits(aw)};
  *(ushort4*)(h2 + (size_t)gn * 256 + lane * 4) = o4;
}

// GEMM2 + fused sd2 epilogue; Wh2b bf16 out.
__global__ __launch_bounds__(256) void k_gemm2(const uint16_t* h2, const uint16_t* Wot,
                                               const float* Aov,
                                               uint16_t* Wh2b, float* s2, float* d2) {
  int w = blockIdx.x * 4 + (threadIdx.x >> 6);  // [0, 512)
  int lane = threadIdx.x & 63;
  int q = lane >> 4, c = lane & 15;
  int g = w >> 8, m0 = (w & 255) << 4;
  const uint16_t* A = h2 + (size_t)g * 4096 * 256;
  const uint16_t* B = Wot + (size_t)g * 64 * 256;
  floatx4 acc[4] = {};
  const uint16_t* arow = A + (size_t)(m0 + c) * 256 + q * 8;
  for (int kk = 0; kk < 8; ++kk) {
    short8 a = *(const short8*)(arow + kk * 32);
#pragma unroll
    for (int t = 0; t < 4; ++t) {
      short8 b = *(const short8*)(B + (size_t)(t * 16 + c) * 256 + kk * 32 + q * 8);
      acc[t] = MFMA16(a, b, acc[t]);
    }
  }
  uint16_t* Crow = Wh2b + (size_t)(g * 4096 + m0) * 64;
#pragma unroll
  for (int t = 0; t < 4; ++t)
#pragma unroll
    for (int r = 0; r < 4; ++r)
      Crow[(size_t)(q * 4 + r) * 64 + t * 16 + c] = f2bf_bits(acc[t][r]);
  const float* ag = Aov + g * 128;
  float as[4], ad[4];
#pragma unroll
  for (int t = 0; t < 4; ++t) { as[t] = ag[t * 16 + c]; ad[t] = ag[64 + t * 16 + c]; }
#pragma unroll
  for (int r = 0; r < 4; ++r) {
    float ps = 0.f, pd = 0.f;
#pragma unroll
    for (int t = 0; t < 4; ++t) { ps += acc[t][r] * as[t]; pd += acc[t][r] * ad[t]; }
#pragma unroll
    for (int o = 1; o < 16; o <<= 1) { ps += __shfl_xor(ps, o); pd += __shfl_xor(pd, o); }
    if (c == 0) {
      int n = m0 + q * 4 + r;
      s2[g * 4096 + n] = ps;
      d2[g * 4096 + n] = pd;
    }
  }
}

// att2 + semantic-attention final, fused. Block = 2 nodes x 2 graphs.
__global__ __launch_bounds__(256) void k_att2f(const int* adj, const int* deg,
    const float* s2, const float* d2, const uint16_t* Wh2b,
    const float* Wp1v, const float* Bp1v, const float* Wp2v,
    const void* sadj, void* out) {
  __shared__ float pbuf[4][MAXDEG];
  __shared__ int jbuf[4][MAXDEG];
  __shared__ float emb_s[4][64];
  __shared__ float st_s[2][32];
  __shared__ float sw_s[2][2];
  int wv = threadIdx.x >> 6, lane = threadIdx.x & 63;
  int g = wv >> 1, nl = wv & 1;
  int n = blockIdx.x * 2 + nl;
  int gn = g * 4096 + n;
  int dg = deg[gn];
  const int* nbr = adj + (size_t)gn * MAXDEG;
  float sn = s2[gn];
  const float* dp = d2 + (size_t)g * 4096;

  bool v0 = lane < dg, v1 = lane + 64 < dg;
  int j0 = 0, j1 = 0;
  if (v0) j0 = nbr[lane];
  if (v1) j1 = nbr[lane + 64];
  float dd0 = dp[j0], dd1 = dp[j1];
  if (v0) jbuf[wv][lane] = j0;
  if (v1) jbuf[wv][lane + 64] = j1;

  const float ninf = -3.0e38f;
  float t0 = sn + dd0; t0 = t0 > 0.f ? t0 : LRELU * t0;
  float t1 = sn + dd1; t1 = t1 > 0.f ? t1 : LRELU * t1;
  float e0 = v0 ? t0 : ninf;
  float e1 = v1 ? t1 : ninf;
  float m = fmaxf(e0, e1);
#pragma unroll
  for (int o = 32; o; o >>= 1) m = fmaxf(m, __shfl_xor(m, o));
  float p0 = v0 ? __expf(e0 - m) : 0.f;
  float p1 = v1 ? __expf(e1 - m) : 0.f;
  float l = p0 + p1;
#pragma unroll
  for (int o = 32; o; o >>= 1) l += __shfl_xor(l, o);
  float inv = __frcp_rn(l);
  pbuf[wv][lane] = p0 * inv;
  pbuf[wv][lane + 64] = p1 * inv;

  int mye = lane >> 4, c4 = lane & 15;
  const uint16_t* Wg = Wh2b + (size_t)g * 4096 * 64;
  float ax = 0.f, ay = 0.f, az = 0.f, aw = 0.f;
  for (int i = 0; i < dg; i += 8) {
    int ia = i + mye, ib = i + 4 + mye;
    bool va = ia < dg, vb = ib < dg;
    int sa_ = va ? ia : 0, sb_ = vb ? ib : 0;
    int ja = jbuf[wv][sa_], jb2 = jbuf[wv][sb_];
    float pa = va ? pbuf[wv][sa_] : 0.f;
    float pb = vb ? pbuf[wv][sb_] : 0.f;
    ushort4 wa = *(const ushort4*)(Wg + (size_t)ja * 64 + c4 * 4);
    ushort4 wb = *(const ushort4*)(Wg + (size_t)jb2 * 64 + c4 * 4);
    ax += pa * bf2f(wa.x) + pb * bf2f(wb.x);
    ay += pa * bf2f(wa.y) + pb * bf2f(wb.y);
    az += pa * bf2f(wa.z) + pb * bf2f(wb.z);
    aw += pa * bf2f(wa.w) + pb * bf2f(wb.w);
  }
#pragma unroll
  for (int o = 16; o <= 32; o <<= 1) {
    ax += __shfl_xor(ax, o);
    ay += __shfl_xor(ay, o);
    az += __shfl_xor(az, o);
    aw += __shfl_xor(aw, o);
  }
  if (lane < 16) {
    ax = ax > 0.f ? ax : __expf(ax) - 1.f;
    ay = ay > 0.f ? ay : __expf(ay) - 1.f;
    az = az > 0.f ? az : __expf(az) - 1.f;
    aw = aw > 0.f ? aw : __expf(aw) - 1.f;
    float4 r = {ax, ay, az, aw};
    *(float4*)&emb_s[wv][c4 * 4] = r;
  }
  __syncthreads();
  if (wv < 2) {
    float e1v = emb_s[wv][lane];       // g=0
    float e2v = emb_s[2 + wv][lane];   // g=1
    if (lane < 32) {
      int gg = lane >> 4, p = lane & 15;
      float s = Bp1v[p];
      const float* eb = emb_s[gg * 2 + wv];
      for (int f = 0; f < 64; ++f) s += eb[f] * Wp1v[f * 16 + p];
      st_s[wv][lane] = tanhf(s);
    }
    if (lane < 2) {
      float s = 0.f;
      for (int p = 0; p < 16; ++p) s += st_s[wv][lane * 16 + p] * Wp2v[p];
      sw_s[wv][lane] = s;
    }
    float w0 = sw_s[wv][0], w1 = sw_s[wv][1];
    float mx = fmaxf(w0, w1);
    float q0 = __expf(w0 - mx), q1 = __expf(w1 - mx);
    float qi = 1.f / (q0 + q1);
    float v = (q0 * e1v + q1 * e2v) * qi;
    if (is_bf16_inputs(sadj)) ((uint16_t*)out)[(size_t)n * 64 + lane] = f2bf_bits(v);
    else ((float*)out)[(size_t)n * 64 + lane] = v;
  }
}

// ---------------------------------------------------------------------------
extern "C" void kernel_launch(void* const* d_in, const int* in_sizes, int n_in,
                              void* d_out, int out_size, void* d_ws, size_t ws_size,
                              hipStream_t stream) {
  const void* x    = d_in[0];
  const void* sadj = d_in[1];
  const void* sadj2 = d_in[2];
  const void* W1  = d_in[3];
  const void* a1  = d_in[4];
  const void* Wo1 = d_in[5];
  const void* ao1 = d_in[6];
  const void* W2  = d_in[7];
  const void* a2  = d_in[8];
  const void* Wo2 = d_in[9];
  const void* ao2 = d_in[10];
  const void* Wp1 = d_in[11];
  const void* bp1 = d_in[12];
  const void* Wp2 = d_in[13];

  char* ws = (char*)d_ws;
  int* adj      = (int*)(ws + OFF_ADJ);
  int* deg      = (int*)(ws + OFF_DEG);
  uint16_t* xb  = (uint16_t*)(ws + OFF_XB);
  uint16_t* Wt  = (uint16_t*)(ws + OFF_WT);
  uint16_t* Wot = (uint16_t*)(ws + OFF_WOT);
  float* Av     = (float*)(ws + OFF_AV);
  float* Aov    = (float*)(ws + OFF_AOV);
  float* Wp1v   = (float*)(ws + OFF_WP1);
  float* Bp1v   = (float*)(ws + OFF_BP1);
  float* Wp2v   = (float*)(ws + OFF_WP2);
  uint16_t* Wh1b = (uint16_t*)(ws + OFF_WH1B);
  float* s1     = (float*)(ws + OFF_S1);
  float* d1     = (float*)(ws + OFF_D1);
  uint16_t* h2  = (uint16_t*)(ws + OFF_H2);
  uint16_t* Wh2b = (uint16_t*)(ws + OFF_WH2B);
  float* s2     = (float*)(ws + OFF_S2);
  float* d2     = (float*)(ws + OFF_D2);

  k_pre_adj<<<9872, 256, 0, stream>>>(sadj, sadj2, x, W1, W2, Wo1, Wo2,
                                      a1, a2, ao1, ao2, Wp1, bp1, Wp2,
                                      adj, deg, xb, Wt, Wot,
                                      Av, Aov, Wp1v, Bp1v, Wp2v);
  k_gemm1<<<512, 256, 0, stream>>>(xb, Wt, Av, Wh1b, s1, d1);
  k_att1<<<2048, 256, 0, stream>>>(adj, deg, s1, d1, Wh1b, h2);
  k_gemm2<<<128, 256, 0, stream>>>(h2, Wot, Aov, Wh2b, s2, d2);
  k_att2f<<<2048, 256, 0, stream>>>(adj, deg, s2, d2, Wh2b,
                                    Wp1v, Bp1v, Wp2v, sadj, d_out);
}